// Round 1
// baseline (315.527 us; speedup 1.0000x reference)
//
#include <hip/hip_runtime.h>
#include <stdint.h>

#define B_DIM 4
#define L_DIM 512
#define D_DIM 768
#define S_DIM 4096
#define DFF_DIM 3072
#define M_DIM (B_DIM * S_DIM)   // 16384

typedef unsigned short ushort_t;
typedef __attribute__((ext_vector_type(8))) short short8;
typedef __attribute__((ext_vector_type(4))) float floatx4;

// round-to-nearest-even fp32 -> bf16 bits
__device__ __forceinline__ ushort_t f2bf(float x) {
  unsigned int u = __float_as_uint(x);
  u += 0x7FFFu + ((u >> 16) & 1u);
  return (ushort_t)(u >> 16);
}

// async 16B global->LDS (wave-uniform base + lane*16 layout required)
__device__ __forceinline__ void load_lds16(const ushort_t* g, ushort_t* lds) {
  __builtin_amdgcn_global_load_lds(
      (const __attribute__((address_space(1))) unsigned int*)g,
      (__attribute__((address_space(3))) unsigned int*)lds, 16, 0, 0);
}

// ---------------------------------------------------------------------------
// Transpose + downcast: in is K x N fp32 row-major, out is N x K bf16 row-major
// K, N multiples of 32. Block = 256 threads handles a 32x32 tile.
// ---------------------------------------------------------------------------
__global__ __launch_bounds__(256)
void transpose_bf16(const float* __restrict__ in, ushort_t* __restrict__ out,
                    int K, int N) {
  __shared__ float tile[32][33];
  const int k0 = blockIdx.x * 32;
  const int n0 = blockIdx.y * 32;
  const int tx = threadIdx.x & 31;
  const int ty = threadIdx.x >> 5;  // 0..7
#pragma unroll
  for (int r = 0; r < 32; r += 8)
    tile[ty + r][tx] = in[(long)(k0 + ty + r) * N + n0 + tx];
  __syncthreads();
#pragma unroll
  for (int r = 0; r < 32; r += 8)
    out[(long)(n0 + ty + r) * K + k0 + tx] = f2bf(tile[tx][ty + r]);
}

// ---------------------------------------------------------------------------
// Span gather + mean: one block per span, 256 threads, 3 columns per thread.
// A[span][d] = mean(h[b][start..end][d]) as bf16.
// ---------------------------------------------------------------------------
__global__ __launch_bounds__(256)
void span_reps(const float* __restrict__ h, const int* __restrict__ span_idx,
               ushort_t* __restrict__ A) {
  const int span = blockIdx.x;       // 0..M-1
  const int b = span >> 12;          // span / S_DIM
  const int tid = threadIdx.x;
  const int start = span_idx[span * 2 + 0];
  const int end   = span_idx[span * 2 + 1];
  const float inv = 1.0f / (float)(end - start + 1);
  const float* hb = h + ((long)b * L_DIM + start) * D_DIM;
  float a0 = 0.f, a1 = 0.f, a2 = 0.f;
  for (int p = start; p <= end; ++p) {
    a0 += hb[tid];
    a1 += hb[tid + 256];
    a2 += hb[tid + 512];
    hb += D_DIM;
  }
  ushort_t* o = A + (long)span * D_DIM;
  o[tid]       = f2bf(a0 * inv);
  o[tid + 256] = f2bf(a1 * inv);
  o[tid + 512] = f2bf(a2 * inv);
}

// ---------------------------------------------------------------------------
// m97-structure bf16 GEMM: C[M][N] = A[M][K] * Bt[N][K]^T (+bias, epilogue)
// 128x128 tile, BK=32, 256 threads (4 waves, each 64x64 via 4x4 of 16x16x32).
// MODE 0: out = relu(acc + bias[col]) -> bf16   (GEMM1 -> Hmid)
// MODE 1: out = acc + bias[col]       -> fp32   (GEMM2 -> final)
// M % 128 == 0, N % 128 == 0, K % 32 == 0.
// ---------------------------------------------------------------------------
template <int MODE>
__global__ __launch_bounds__(256)
void gemm_bt(const ushort_t* __restrict__ A, const ushort_t* __restrict__ Bt,
             const float* __restrict__ bias, void* __restrict__ Cv,
             int M, int N, int K) {
  __shared__ ushort_t As[128 * 32];
  __shared__ ushort_t Bs[128 * 32];

  const int tid  = threadIdx.x;
  const int lane = tid & 63;
  const int wave = tid >> 6;
  const int l16  = lane & 15;
  const int quad = lane >> 4;

  const int bm = blockIdx.x;
  const int bn = blockIdx.y;

  const int wm = (wave & 1) * 64;
  const int wn = (wave >> 1) * 64;

  floatx4 acc[4][4];
#pragma unroll
  for (int i = 0; i < 4; ++i)
#pragma unroll
    for (int j = 0; j < 4; ++j)
      acc[i][j] = (floatx4)0.0f;

  // staging: 512 16B segments per tile; seg s -> row = s>>2, kchunk = (s&3)*8
  const int s0 = tid, s1 = tid + 256;
  const ushort_t* gA0 = A + (long)(bm * 128 + (s0 >> 2)) * K + (s0 & 3) * 8;
  const ushort_t* gA1 = A + (long)(bm * 128 + (s1 >> 2)) * K + (s1 & 3) * 8;
  const ushort_t* gB0 = Bt + (long)(bn * 128 + (s0 >> 2)) * K + (s0 & 3) * 8;
  const ushort_t* gB1 = Bt + (long)(bn * 128 + (s1 >> 2)) * K + (s1 & 3) * 8;
  ushort_t* lA0 = As + s0 * 8;
  ushort_t* lA1 = As + s1 * 8;
  ushort_t* lB0 = Bs + s0 * 8;
  ushort_t* lB1 = Bs + s1 * 8;

  for (int k0 = 0; k0 < K; k0 += 32) {
    load_lds16(gA0, lA0);
    load_lds16(gA1, lA1);
    load_lds16(gB0, lB0);
    load_lds16(gB1, lB1);
    gA0 += 32; gA1 += 32; gB0 += 32; gB1 += 32;
    __syncthreads();  // compiler drains vmcnt before s_barrier

    short8 af[4], bf[4];
#pragma unroll
    for (int i = 0; i < 4; ++i)
      af[i] = *(const short8*)(As + (wm + i * 16 + l16) * 32 + quad * 8);
#pragma unroll
    for (int j = 0; j < 4; ++j)
      bf[j] = *(const short8*)(Bs + (wn + j * 16 + l16) * 32 + quad * 8);
#pragma unroll
    for (int i = 0; i < 4; ++i)
#pragma unroll
      for (int j = 0; j < 4; ++j)
        acc[i][j] = __builtin_amdgcn_mfma_f32_16x16x32_bf16(af[i], bf[j], acc[i][j], 0, 0, 0);
    __syncthreads();
  }

  // epilogue: C/D layout col = lane&15, row = quad*4 + r
#pragma unroll
  for (int i = 0; i < 4; ++i) {
#pragma unroll
    for (int j = 0; j < 4; ++j) {
      const int col = bn * 128 + wn + j * 16 + l16;
      const float bv = bias[col];
      const int row0 = bm * 128 + wm + i * 16 + quad * 4;
#pragma unroll
      for (int r = 0; r < 4; ++r) {
        float v = acc[i][j][r] + bv;
        if (MODE == 0) {
          v = v > 0.0f ? v : 0.0f;
          ((ushort_t*)Cv)[(long)(row0 + r) * N + col] = f2bf(v);
        } else {
          ((float*)Cv)[(long)(row0 + r) * N + col] = v;
        }
      }
    }
  }
}

extern "C" void kernel_launch(void* const* d_in, const int* in_sizes, int n_in,
                              void* d_out, int out_size, void* d_ws, size_t ws_size,
                              hipStream_t stream) {
  const float* h        = (const float*)d_in[0];
  const int*   span_idx = (const int*)d_in[1];
  const float* W1       = (const float*)d_in[2];
  const float* b1       = (const float*)d_in[3];
  const float* W2       = (const float*)d_in[4];
  const float* b2       = (const float*)d_in[5];
  float* out = (float*)d_out;

  // workspace layout (bf16 elements): A | W1T | W2T | Hmid  (~135 MB total)
  ushort_t* A   = (ushort_t*)d_ws;
  ushort_t* W1T = A + (size_t)M_DIM * D_DIM;
  ushort_t* W2T = W1T + (size_t)DFF_DIM * D_DIM;
  ushort_t* Hm  = W2T + (size_t)D_DIM * DFF_DIM;

  // W1 (D x DFF) -> W1T (DFF x D) bf16 ; W2 (DFF x D) -> W2T (D x DFF) bf16
  transpose_bf16<<<dim3(D_DIM / 32, DFF_DIM / 32), 256, 0, stream>>>(W1, W1T, D_DIM, DFF_DIM);
  transpose_bf16<<<dim3(DFF_DIM / 32, D_DIM / 32), 256, 0, stream>>>(W2, W2T, DFF_DIM, D_DIM);

  span_reps<<<M_DIM, 256, 0, stream>>>(h, span_idx, A);

  // GEMM1: A (M x D) * W1 (D x DFF) + b1, relu -> Hmid bf16 (M x DFF)
  gemm_bt<0><<<dim3(M_DIM / 128, DFF_DIM / 128), 256, 0, stream>>>(
      A, W1T, b1, Hm, M_DIM, DFF_DIM, D_DIM);

  // GEMM2: Hmid (M x DFF) * W2 (DFF x D) + b2 -> out fp32 (M x D)
  gemm_bt<1><<<dim3(M_DIM / 128, D_DIM / 128), 256, 0, stream>>>(
      Hm, W2T, b2, out, M_DIM, D_DIM, DFF_DIM);
}

// Round 2
// 304.145 us; speedup vs baseline: 1.0374x; 1.0374x over previous
//
#include <hip/hip_runtime.h>
#include <stdint.h>

#define B_DIM 4
#define L_DIM 512
#define D_DIM 768
#define S_DIM 4096
#define DFF_DIM 3072
#define M_DIM (B_DIM * S_DIM)   // 16384

typedef unsigned short ushort_t;
typedef __attribute__((ext_vector_type(8))) short short8;
typedef __attribute__((ext_vector_type(4))) float floatx4;

// round-to-nearest-even fp32 -> bf16 bits
__device__ __forceinline__ ushort_t f2bf(float x) {
  unsigned int u = __float_as_uint(x);
  u += 0x7FFFu + ((u >> 16) & 1u);
  return (ushort_t)(u >> 16);
}

// async 16B global->LDS (wave-uniform base + lane*16 layout required)
__device__ __forceinline__ void load_lds16(const ushort_t* g, ushort_t* lds) {
  __builtin_amdgcn_global_load_lds(
      (const __attribute__((address_space(1))) unsigned int*)g,
      (__attribute__((address_space(3))) unsigned int*)lds, 16, 0, 0);
}

// ---------------------------------------------------------------------------
// Transpose + downcast: in is K x N fp32 row-major, out is N x K bf16 row-major
// ---------------------------------------------------------------------------
__global__ __launch_bounds__(256)
void transpose_bf16(const float* __restrict__ in, ushort_t* __restrict__ out,
                    int K, int N) {
  __shared__ float tile[32][33];
  const int k0 = blockIdx.x * 32;
  const int n0 = blockIdx.y * 32;
  const int tx = threadIdx.x & 31;
  const int ty = threadIdx.x >> 5;  // 0..7
#pragma unroll
  for (int r = 0; r < 32; r += 8)
    tile[ty + r][tx] = in[(long)(k0 + ty + r) * N + n0 + tx];
  __syncthreads();
#pragma unroll
  for (int r = 0; r < 32; r += 8)
    out[(long)(n0 + ty + r) * K + k0 + tx] = f2bf(tile[tx][ty + r]);
}

// ---------------------------------------------------------------------------
// Span gather + mean: one block per span, 256 threads, 3 columns per thread.
// ---------------------------------------------------------------------------
__global__ __launch_bounds__(256)
void span_reps(const float* __restrict__ h, const int* __restrict__ span_idx,
               ushort_t* __restrict__ A) {
  const int span = blockIdx.x;       // 0..M-1
  const int b = span >> 12;          // span / S_DIM
  const int tid = threadIdx.x;
  const int start = span_idx[span * 2 + 0];
  const int end   = span_idx[span * 2 + 1];
  const float inv = 1.0f / (float)(end - start + 1);
  const float* hb = h + ((long)b * L_DIM + start) * D_DIM;
  float a0 = 0.f, a1 = 0.f, a2 = 0.f;
  for (int p = start; p <= end; ++p) {
    a0 += hb[tid];
    a1 += hb[tid + 256];
    a2 += hb[tid + 512];
    hb += D_DIM;
  }
  ushort_t* o = A + (long)span * D_DIM;
  o[tid]       = f2bf(a0 * inv);
  o[tid + 256] = f2bf(a1 * inv);
  o[tid + 512] = f2bf(a2 * inv);
}

// ---------------------------------------------------------------------------
// bf16 GEMM: C[M][N] = A[M][K] * Bt[N][K]^T (+bias epilogue)
// 128x128 tile, BK=64 as two BK=32 LDS panels (keeps 64-B row stride and
// global_load_lds lane-contiguity), 256 threads = 4 waves, each wave 64x64
// via 4x4 grid of 16x16x32 MFMA. One barrier pair per 64 K-steps.
// MODE 0: out = relu(acc + bias[col]) -> bf16   (GEMM1 -> Hmid)
// MODE 1: out = acc + bias[col]       -> fp32   (GEMM2 -> final)
// M % 128 == 0, N % 128 == 0, K % 64 == 0.
// ---------------------------------------------------------------------------
template <int MODE>
__global__ __launch_bounds__(256)
void gemm_bt(const ushort_t* __restrict__ A, const ushort_t* __restrict__ Bt,
             const float* __restrict__ bias, void* __restrict__ Cv,
             int M, int N, int K) {
  __shared__ ushort_t As[2][128 * 32];
  __shared__ ushort_t Bs[2][128 * 32];

  const int tid  = threadIdx.x;
  const int lane = tid & 63;
  const int wave = tid >> 6;
  const int l16  = lane & 15;
  const int quad = lane >> 4;

  const int bm = blockIdx.x;
  const int bn = blockIdx.y;

  const int wm = (wave & 1) * 64;
  const int wn = (wave >> 1) * 64;

  floatx4 acc[4][4];
#pragma unroll
  for (int i = 0; i < 4; ++i)
#pragma unroll
    for (int j = 0; j < 4; ++j)
      acc[i][j] = (floatx4)0.0f;

  // staging: per panel, 512 16B segments; seg s -> row = s>>2, kchunk = (s&3)*8
  const int s0 = tid, s1 = tid + 256;
  const int rA0 = s0 >> 2, cA0 = (s0 & 3) * 8;
  const int rA1 = s1 >> 2, cA1 = (s1 & 3) * 8;
  const ushort_t* gA0 = A + (long)(bm * 128 + rA0) * K + cA0;
  const ushort_t* gA1 = A + (long)(bm * 128 + rA1) * K + cA1;
  const ushort_t* gB0 = Bt + (long)(bn * 128 + rA0) * K + cA0;
  const ushort_t* gB1 = Bt + (long)(bn * 128 + rA1) * K + cA1;
  ushort_t* lA0 = &As[0][0] + s0 * 8;
  ushort_t* lA1 = &As[0][0] + s1 * 8;
  ushort_t* lB0 = &Bs[0][0] + s0 * 8;
  ushort_t* lB1 = &Bs[0][0] + s1 * 8;
  const int PANEL = 128 * 32;  // elements per panel

  for (int k0 = 0; k0 < K; k0 += 64) {
    // panel 0: k in [k0, k0+32), panel 1: k in [k0+32, k0+64)
    load_lds16(gA0, lA0);
    load_lds16(gA1, lA1);
    load_lds16(gB0, lB0);
    load_lds16(gB1, lB1);
    load_lds16(gA0 + 32, lA0 + PANEL);
    load_lds16(gA1 + 32, lA1 + PANEL);
    load_lds16(gB0 + 32, lB0 + PANEL);
    load_lds16(gB1 + 32, lB1 + PANEL);
    gA0 += 64; gA1 += 64; gB0 += 64; gB1 += 64;
    __syncthreads();  // drains vmcnt; one barrier pair per 64 K-steps

#pragma unroll
    for (int p = 0; p < 2; ++p) {
      short8 af[4], bf[4];
#pragma unroll
      for (int i = 0; i < 4; ++i)
        af[i] = *(const short8*)(&As[p][0] + (wm + i * 16 + l16) * 32 + quad * 8);
#pragma unroll
      for (int j = 0; j < 4; ++j)
        bf[j] = *(const short8*)(&Bs[p][0] + (wn + j * 16 + l16) * 32 + quad * 8);
#pragma unroll
      for (int i = 0; i < 4; ++i)
#pragma unroll
        for (int j = 0; j < 4; ++j)
          acc[i][j] = __builtin_amdgcn_mfma_f32_16x16x32_bf16(af[i], bf[j], acc[i][j], 0, 0, 0);
    }
    __syncthreads();
  }

  // epilogue: C/D layout col = lane&15, row = quad*4 + r
#pragma unroll
  for (int i = 0; i < 4; ++i) {
#pragma unroll
    for (int j = 0; j < 4; ++j) {
      const int col = bn * 128 + wn + j * 16 + l16;
      const float bv = bias[col];
      const int row0 = bm * 128 + wm + i * 16 + quad * 4;
#pragma unroll
      for (int r = 0; r < 4; ++r) {
        float v = acc[i][j][r] + bv;
        if (MODE == 0) {
          v = v > 0.0f ? v : 0.0f;
          ((ushort_t*)Cv)[(long)(row0 + r) * N + col] = f2bf(v);
        } else {
          ((float*)Cv)[(long)(row0 + r) * N + col] = v;
        }
      }
    }
  }
}

extern "C" void kernel_launch(void* const* d_in, const int* in_sizes, int n_in,
                              void* d_out, int out_size, void* d_ws, size_t ws_size,
                              hipStream_t stream) {
  const float* h        = (const float*)d_in[0];
  const int*   span_idx = (const int*)d_in[1];
  const float* W1       = (const float*)d_in[2];
  const float* b1       = (const float*)d_in[3];
  const float* W2       = (const float*)d_in[4];
  const float* b2       = (const float*)d_in[5];
  float* out = (float*)d_out;

  // workspace layout (bf16 elements): A | W1T | W2T | Hmid
  ushort_t* A   = (ushort_t*)d_ws;
  ushort_t* W1T = A + (size_t)M_DIM * D_DIM;
  ushort_t* W2T = W1T + (size_t)DFF_DIM * D_DIM;
  ushort_t* Hm  = W2T + (size_t)D_DIM * DFF_DIM;

  transpose_bf16<<<dim3(D_DIM / 32, DFF_DIM / 32), 256, 0, stream>>>(W1, W1T, D_DIM, DFF_DIM);
  transpose_bf16<<<dim3(DFF_DIM / 32, D_DIM / 32), 256, 0, stream>>>(W2, W2T, DFF_DIM, D_DIM);

  span_reps<<<M_DIM, 256, 0, stream>>>(h, span_idx, A);

  // GEMM1: A (M x D) * W1 (D x DFF) + b1, relu -> Hmid bf16 (M x DFF)
  gemm_bt<0><<<dim3(M_DIM / 128, DFF_DIM / 128), 256, 0, stream>>>(
      A, W1T, b1, Hm, M_DIM, DFF_DIM, D_DIM);

  // GEMM2: Hmid (M x DFF) * W2 (DFF x D) + b2 -> out fp32 (M x D)
  gemm_bt<1><<<dim3(M_DIM / 128, D_DIM / 128), 256, 0, stream>>>(
      Hm, W2T, b2, out, M_DIM, D_DIM, DFF_DIM);
}